// Round 2
// baseline (1688.116 us; speedup 1.0000x reference)
//
#include <hip/hip_runtime.h>

// CompetitiveLayer: K = param^2 (4096x4096 f32), 21 fixed-point iterations of
//   AF = AT/(1+K@BF); BF = BT/(1+AF@K)   -> 42 dependent matvec phases,
// then C = K * AF[:,None] * BF[None,:].
//
// Strategy: K fits in the chip's register files (256 blocks x 256 lanes x
// 256 f32 = 64 MiB). Load+square K once into VGPRs, run all 42 phases inside
// one persistent kernel, communicating 4096-float vectors through d_ws with
// device-scope atomics and a hand-rolled monotonic grid barrier (NO
// hipLaunchCooperativeKernel — its silent launch failure was round 1's bug).
// 1 block/CU co-residency is guaranteed by __launch_bounds__(256,1).

constexpr int N      = 4096;
constexpr int NPHASE = 42;
constexpr int NBLK   = 256;

// Device-scope (coherent-point) load/store for cross-block scratch traffic.
__device__ __forceinline__ float ld_agent(const float* p) {
    return __hip_atomic_load(p, __ATOMIC_RELAXED, __HIP_MEMORY_SCOPE_AGENT);
}
__device__ __forceinline__ void st_agent(float* p, float v) {
    __hip_atomic_store(p, v, __ATOMIC_RELAXED, __HIP_MEMORY_SCOPE_AGENT);
}

// Block (bR,bC) owns the 256x256 tile of K at rows [256*bR,+256), cols
// [256*bC,+256). Lane (rl,cl) owns the 16x16 sub-tile — in k[256] VGPRs for
// the whole kernel.
__global__ void __launch_bounds__(256, 1)
competitive_persistent(const float* __restrict__ AT, const float* __restrict__ BT,
                       const float* __restrict__ P,  float* __restrict__ C,
                       float* __restrict__ ws)
{
    const int b  = blockIdx.x;       // 0..255
    const int t  = threadIdx.x;      // 0..255
    const int bR = b >> 4, bC = b & 15;
    const int R0 = bR << 8, C0 = bC << 8;
    const int rl = t >> 4, cl = t & 15;
    const int row0 = R0 + rl * 16;
    const int col0 = C0 + cl * 16;

    unsigned* bar = (unsigned*)(ws + 3 * (size_t)N);   // barrier counter (host-zeroed)

    // ---- Load K = param^2 into registers (whole chip holds all 64 MiB) ----
    float k[256];
    #pragma unroll
    for (int r = 0; r < 16; ++r) {
        const float4* src = (const float4*)(P + (size_t)(row0 + r) * N + col0);
        #pragma unroll
        for (int q = 0; q < 4; ++q) {
            float4 v = src[q];
            k[r * 16 + q * 4 + 0] = v.x * v.x;
            k[r * 16 + q * 4 + 1] = v.y * v.y;
            k[r * 16 + q * 4 + 2] = v.z * v.z;
            k[r * 16 + q * 4 + 3] = v.w * v.w;
        }
    }

    __shared__ __align__(16) float xsh[256];
    __shared__ __align__(16) float red[1024];

    // Rotating 3-buffer scratch (each N floats, host-zeroed):
    //   phase ph accumulates into buf[ph%3], reads buf[(ph+2)%3] (== ph-1),
    //   zeroes buf[(ph+1)%3] (the accumulator of phase ph+1).
    // Phase 0 reads the zeroed buffer -> BF = BT/(1+0) = BT, matching iter 1.
    #pragma unroll 1
    for (int ph = 0; ph < NPHASE; ++ph) {
        float*       D = ws + (size_t)N * (ph % 3);
        const float* S = ws + (size_t)N * ((ph + 2) % 3);
        float*       Z = ws + (size_t)N * ((ph + 1) % 3);
        const bool rowPhase = ((ph & 1) == 0);

        // Stage x-vector slice for this block into LDS (1 divide/thread).
        {
            const int    base = rowPhase ? C0 : R0;
            const float* T    = rowPhase ? BT : AT;
            const float  s    = ld_agent(S + base + t);
            xsh[t] = T[base + t] / (1.0f + s);
        }
        // Zero the buffer phase ph+1 will accumulate into (race-free: its
        // last readers finished at phase ph-1, before the last barrier).
        if (t < 16) st_agent(Z + b * 16 + t, 0.0f);
        __syncthreads();

        if (rowPhase) {
            // y[i] += sum_j K[i,j]*BF[j] over this lane's 16 cols
            float xv[16];
            const float4* xs4 = (const float4*)(xsh + cl * 16);
            #pragma unroll
            for (int q = 0; q < 4; ++q) {
                float4 v = xs4[q];
                xv[q * 4 + 0] = v.x; xv[q * 4 + 1] = v.y;
                xv[q * 4 + 2] = v.z; xv[q * 4 + 3] = v.w;
            }
            float part[16];
            #pragma unroll
            for (int r = 0; r < 16; ++r) part[r] = 0.0f;
            #pragma unroll
            for (int c = 0; c < 16; ++c) {
                const float x = xv[c];
                #pragma unroll
                for (int r = 0; r < 16; ++r)
                    part[r] = fmaf(k[r * 16 + c], x, part[r]);
            }
            // Reduce across the 16 cl-lanes (lane-id bits 0..3, in-wave).
            #pragma unroll
            for (int off = 1; off < 16; off <<= 1) {
                #pragma unroll
                for (int r = 0; r < 16; ++r)
                    part[r] += __shfl_xor(part[r], off, 64);
            }
            if (cl == 0) {
                #pragma unroll
                for (int r = 0; r < 16; ++r)
                    atomicAdd(D + row0 + r, part[r]);   // 16-way contention
            }
        } else {
            // y[j] += sum_i AF[i]*K[i,j] over this lane's 16 rows
            float av[16];
            #pragma unroll
            for (int r = 0; r < 16; ++r) av[r] = xsh[rl * 16 + r];
            float part[16];
            #pragma unroll
            for (int c = 0; c < 16; ++c) part[c] = 0.0f;
            #pragma unroll
            for (int r = 0; r < 16; ++r) {
                const float a = av[r];
                #pragma unroll
                for (int c = 0; c < 16; ++c)
                    part[c] = fmaf(k[r * 16 + c], a, part[c]);
            }
            // Reduce across rl within the wave (lane-id bits 4,5).
            #pragma unroll
            for (int c = 0; c < 16; ++c) {
                part[c] += __shfl_xor(part[c], 16, 64);
                part[c] += __shfl_xor(part[c], 32, 64);
            }
            const int w = t >> 6;                 // wave id 0..3
            if ((t & 63) < 16) {                  // one lane per cl per wave
                #pragma unroll
                for (int c = 0; c < 16; ++c)
                    red[w * 256 + cl * 16 + c] = part[c];
            }
            __syncthreads();
            const float s4 = red[t] + red[256 + t] + red[512 + t] + red[768 + t];
            atomicAdd(D + C0 + t, s4);            // 16-way contention
        }

        // ---- Manual grid barrier (monotonic counter, no reset) ----
        __threadfence();          // release all prior device-scope writes
        __syncthreads();          // whole block done (drains wave stores)
        if (t == 0) {
            __hip_atomic_fetch_add(bar, 1u, __ATOMIC_ACQ_REL,
                                   __HIP_MEMORY_SCOPE_AGENT);
            const unsigned target = (unsigned)(NBLK * (ph + 1));
            while (__hip_atomic_load(bar, __ATOMIC_ACQUIRE,
                                     __HIP_MEMORY_SCOPE_AGENT) < target)
                __builtin_amdgcn_s_sleep(2);
        }
        __syncthreads();
    }

    // ---- Epilogue: C = K * AF[:,None] * BF[None,:] ----
    // Row result of phase 40 -> buf[40%3]=buf1; col result of 41 -> buf2.
    const float* yrow = ws + (size_t)N * 1;
    const float* ycol = ws + (size_t)N * 2;
    xsh[t] = AT[R0 + t] / (1.0f + ld_agent(yrow + R0 + t));   // AF slice
    red[t] = BT[C0 + t] / (1.0f + ld_agent(ycol + C0 + t));   // BF slice
    __syncthreads();

    float af[16], bf[16];
    #pragma unroll
    for (int r = 0; r < 16; ++r) af[r] = xsh[rl * 16 + r];
    #pragma unroll
    for (int c = 0; c < 16; ++c) bf[c] = red[cl * 16 + c];

    #pragma unroll
    for (int r = 0; r < 16; ++r) {
        float4* dst = (float4*)(C + (size_t)(row0 + r) * N + col0);
        const float a = af[r];
        #pragma unroll
        for (int q = 0; q < 4; ++q) {
            float4 o;
            o.x = k[r * 16 + q * 4 + 0] * a * bf[q * 4 + 0];
            o.y = k[r * 16 + q * 4 + 1] * a * bf[q * 4 + 1];
            o.z = k[r * 16 + q * 4 + 2] * a * bf[q * 4 + 2];
            o.w = k[r * 16 + q * 4 + 3] * a * bf[q * 4 + 3];
            dst[q] = o;
        }
    }
}

extern "C" void kernel_launch(void* const* d_in, const int* in_sizes, int n_in,
                              void* d_out, int out_size, void* d_ws, size_t ws_size,
                              hipStream_t stream) {
    const float* AT = (const float*)d_in[0];
    const float* BT = (const float*)d_in[1];
    const float* P  = (const float*)d_in[2];
    float*       C  = (float*)d_out;
    float*       ws = (float*)d_ws;

    // Zero the 3 rotating accumulator buffers + barrier counter
    // (d_ws is re-poisoned to 0xAA before every timed call).
    hipMemsetAsync(d_ws, 0, (3 * (size_t)N + 16) * sizeof(float), stream);

    competitive_persistent<<<dim3(NBLK), dim3(256), 0, stream>>>(AT, BT, P, C, ws);
}

// Round 3
// 1655.399 us; speedup vs baseline: 1.0198x; 1.0198x over previous
//
#include <hip/hip_runtime.h>

// CompetitiveLayer: K = param^2 (4096x4096 f32), 21 fixed-point iterations of
//   AF = AT/(1+K@BF); BF = BT/(1+AF@K)   -> 42 dependent matvec phases,
// then C = K * AF[:,None] * BF[None,:].
//
// Strategy: K lives in VGPRs (256 blocks x 256 lanes x 256 f32 = 64 MiB =
// half the chip's 128 MiB register file). Load+square K once, run all 42
// phases in one persistent kernel, vectors communicated through d_ws with
// device-scope atomics + hand-rolled monotonic grid barrier.
//
// R2 post-mortem: __launch_bounds__(256,1) only sets MIN waves/EU — the
// allocator targeted 3 waves/EU (VGPR_Count=168=512/3) and spilled k[] to
// scratch -> latency-bound reload at 1 wave/SIMD, VALUBusy 1.4%, 1688 us.
// Fix: amdgpu_waves_per_eu(1,1) pins occupancy to 1 wave/EU -> 512-VGPR
// budget -> k[256] stays resident.

constexpr int N      = 4096;
constexpr int NPHASE = 42;
constexpr int NBLK   = 256;

__device__ __forceinline__ float ld_agent(const float* p) {
    return __hip_atomic_load(p, __ATOMIC_RELAXED, __HIP_MEMORY_SCOPE_AGENT);
}
__device__ __forceinline__ void st_agent(float* p, float v) {
    __hip_atomic_store(p, v, __ATOMIC_RELAXED, __HIP_MEMORY_SCOPE_AGENT);
}

// Block (bR,bC) owns the 256x256 tile of K at rows [256*bR,+256), cols
// [256*bC,+256). Lane (rl,cl) owns a 16x16 sub-tile in k[256] VGPRs.
__global__ void __launch_bounds__(256)
__attribute__((amdgpu_waves_per_eu(1, 1)))
competitive_persistent(const float* __restrict__ AT, const float* __restrict__ BT,
                       const float* __restrict__ P,  float* __restrict__ C,
                       float* __restrict__ ws)
{
    const int b  = blockIdx.x;       // 0..255
    const int t  = threadIdx.x;      // 0..255
    const int bR = b >> 4, bC = b & 15;
    const int R0 = bR << 8, C0 = bC << 8;
    const int rl = t >> 4, cl = t & 15;
    const int row0 = R0 + rl * 16;
    const int col0 = C0 + cl * 16;

    unsigned* bar = (unsigned*)(ws + 3 * (size_t)N);   // barrier counter (host-zeroed)

    // ---- Load K = param^2 into registers ----
    float k[256];
    #pragma unroll
    for (int r = 0; r < 16; ++r) {
        const float4* src = (const float4*)(P + (size_t)(row0 + r) * N + col0);
        #pragma unroll
        for (int q = 0; q < 4; ++q) {
            float4 v = src[q];
            k[r * 16 + q * 4 + 0] = v.x * v.x;
            k[r * 16 + q * 4 + 1] = v.y * v.y;
            k[r * 16 + q * 4 + 2] = v.z * v.z;
            k[r * 16 + q * 4 + 3] = v.w * v.w;
        }
    }

    __shared__ __align__(16) float xsh[256];
    __shared__ __align__(16) float red[1024];

    // Rotating 3-buffer scratch (each N floats, host-zeroed):
    //   phase ph accumulates into buf[ph%3], reads buf[(ph+2)%3] (== ph-1),
    //   zeroes buf[(ph+1)%3] (the accumulator of phase ph+1).
    // Phase 0 reads the zeroed buffer -> BF = BT/(1+0) = BT, matching iter 1.
    #pragma unroll 1
    for (int ph = 0; ph < NPHASE; ++ph) {
        float*       D = ws + (size_t)N * (ph % 3);
        const float* S = ws + (size_t)N * ((ph + 2) % 3);
        float*       Z = ws + (size_t)N * ((ph + 1) % 3);
        const bool rowPhase = ((ph & 1) == 0);

        // Stage x-vector slice for this block into LDS (1 divide/thread).
        {
            const int    base = rowPhase ? C0 : R0;
            const float* T    = rowPhase ? BT : AT;
            const float  s    = ld_agent(S + base + t);
            xsh[t] = T[base + t] / (1.0f + s);
        }
        // Zero the buffer phase ph+1 will accumulate into (race-free: its
        // last readers finished before the previous barrier).
        if (t < 16) st_agent(Z + b * 16 + t, 0.0f);
        __syncthreads();

        if (rowPhase) {
            // y[i] += sum_j K[i,j]*BF[j] over this lane's 16 cols
            float xv[16];
            const float4* xs4 = (const float4*)(xsh + cl * 16);
            #pragma unroll
            for (int q = 0; q < 4; ++q) {
                float4 v = xs4[q];
                xv[q * 4 + 0] = v.x; xv[q * 4 + 1] = v.y;
                xv[q * 4 + 2] = v.z; xv[q * 4 + 3] = v.w;
            }
            float part[16];
            #pragma unroll
            for (int r = 0; r < 16; ++r) part[r] = 0.0f;
            #pragma unroll
            for (int c = 0; c < 16; ++c) {
                const float x = xv[c];
                #pragma unroll
                for (int r = 0; r < 16; ++r)
                    part[r] = fmaf(k[r * 16 + c], x, part[r]);
            }
            // Reduce across the 16 cl-lanes (lane-id bits 0..3, in-wave).
            #pragma unroll
            for (int off = 1; off < 16; off <<= 1) {
                #pragma unroll
                for (int r = 0; r < 16; ++r)
                    part[r] += __shfl_xor(part[r], off, 64);
            }
            if (cl == 0) {
                #pragma unroll
                for (int r = 0; r < 16; ++r)
                    atomicAdd(D + row0 + r, part[r]);   // 16-way contention
            }
        } else {
            // y[j] += sum_i AF[i]*K[i,j] over this lane's 16 rows
            float av[16];
            #pragma unroll
            for (int r = 0; r < 16; ++r) av[r] = xsh[rl * 16 + r];
            float part[16];
            #pragma unroll
            for (int c = 0; c < 16; ++c) part[c] = 0.0f;
            #pragma unroll
            for (int r = 0; r < 16; ++r) {
                const float a = av[r];
                #pragma unroll
                for (int c = 0; c < 16; ++c)
                    part[c] = fmaf(k[r * 16 + c], a, part[c]);
            }
            // Reduce across rl within the wave (lane-id bits 4,5).
            #pragma unroll
            for (int c = 0; c < 16; ++c) {
                part[c] += __shfl_xor(part[c], 16, 64);
                part[c] += __shfl_xor(part[c], 32, 64);
            }
            const int w = t >> 6;                 // wave id 0..3
            if ((t & 63) < 16) {                  // one lane per cl per wave
                #pragma unroll
                for (int c = 0; c < 16; ++c)
                    red[w * 256 + cl * 16 + c] = part[c];
            }
            __syncthreads();
            const float s4 = red[t] + red[256 + t] + red[512 + t] + red[768 + t];
            atomicAdd(D + C0 + t, s4);            // 16-way contention
        }

        // ---- Manual grid barrier (monotonic counter, no reset) ----
        __threadfence();          // release all prior device-scope writes
        __syncthreads();          // whole block done (drains wave stores)
        if (t == 0) {
            __hip_atomic_fetch_add(bar, 1u, __ATOMIC_ACQ_REL,
                                   __HIP_MEMORY_SCOPE_AGENT);
            const unsigned target = (unsigned)(NBLK * (ph + 1));
            while (__hip_atomic_load(bar, __ATOMIC_ACQUIRE,
                                     __HIP_MEMORY_SCOPE_AGENT) < target)
                __builtin_amdgcn_s_sleep(2);
        }
        __syncthreads();
    }

    // ---- Epilogue: C = K * AF[:,None] * BF[None,:] ----
    // Row result of phase 40 -> buf[40%3]=buf1; col result of 41 -> buf2.
    const float* yrow = ws + (size_t)N * 1;
    const float* ycol = ws + (size_t)N * 2;
    xsh[t] = AT[R0 + t] / (1.0f + ld_agent(yrow + R0 + t));   // AF slice
    red[t] = BT[C0 + t] / (1.0f + ld_agent(ycol + C0 + t));   // BF slice
    __syncthreads();

    float af[16], bf[16];
    #pragma unroll
    for (int r = 0; r < 16; ++r) af[r] = xsh[rl * 16 + r];
    #pragma unroll
    for (int c = 0; c < 16; ++c) bf[c] = red[cl * 16 + c];

    #pragma unroll
    for (int r = 0; r < 16; ++r) {
        float4* dst = (float4*)(C + (size_t)(row0 + r) * N + col0);
        const float a = af[r];
        #pragma unroll
        for (int q = 0; q < 4; ++q) {
            float4 o;
            o.x = k[r * 16 + q * 4 + 0] * a * bf[q * 4 + 0];
            o.y = k[r * 16 + q * 4 + 1] * a * bf[q * 4 + 1];
            o.z = k[r * 16 + q * 4 + 2] * a * bf[q * 4 + 2];
            o.w = k[r * 16 + q * 4 + 3] * a * bf[q * 4 + 3];
            dst[q] = o;
        }
    }
}

extern "C" void kernel_launch(void* const* d_in, const int* in_sizes, int n_in,
                              void* d_out, int out_size, void* d_ws, size_t ws_size,
                              hipStream_t stream) {
    const float* AT = (const float*)d_in[0];
    const float* BT = (const float*)d_in[1];
    const float* P  = (const float*)d_in[2];
    float*       C  = (float*)d_out;
    float*       ws = (float*)d_ws;

    // Zero the 3 rotating accumulator buffers + barrier counter
    // (d_ws is re-poisoned to 0xAA before every timed call).
    hipMemsetAsync(d_ws, 0, (3 * (size_t)N + 16) * sizeof(float), stream);

    competitive_persistent<<<dim3(NBLK), dim3(256), 0, stream>>>(AT, BT, P, C, ws);
}